// Round 7
// baseline (211.591 us; speedup 1.0000x reference)
//
#include <hip/hip_runtime.h>
#include <cmath>

#define NT 144
#define ROWS_PER_BLOCK 64
#define F4_PER_BLOCK (ROWS_PER_BLOCK * NT / 4)   // 2304 float4 per block

typedef float v4f __attribute__((ext_vector_type(4)));

// Round-9: CALIBRATED DIAGNOSTIC (structure = R6, byte-identical I/O path).
// Six rounds of structural changes (occupancy, scalar-vs-packed, dep-chain,
// LDS prefetch, NT stores, strided-vs-linear store layout) produced ZERO
// movement: total is pinned at 175-180 us with the poison fill invariant at
// 91-96 us. The kernel's own rocprof row has NEVER been visible (top-5 is
// saturated by fills), so "kernel = 83 us" is an inference, not a measurement.
// This round doubles the per-element math through asm-opaqued copies
// (CSE-proof) and averages bit-exactly: 0.5*(r+r) == r in f32.
//   Outcome A: total ~250 us, kernel surfaces at ~150-165 us, VALUBusy high
//              -> kernel is ~83 us compute-bound; attack trans/FMA next.
//   Outcome B: kernel surfaces ~95-120 us, VALUBusy low -> latency-bound;
//              read its counters for the true bottleneck.
//   Outcome C: total ~176, kernel still hidden -> base kernel < 50 us and
//              dur_us carries >= 40 us fixed harness cost -> harness floor.

__global__ __launch_bounds__(256, 4) void dynangio_kernel(
    const float* __restrict__ x,
    const float* __restrict__ t,
    const float* __restrict__ alpha,
    const float* __restrict__ R,
    float* __restrict__ out,
    int B)
{
    __shared__ alignas(16) float sh_t[NT];
    __shared__ alignas(16) float sh_re[NT];
    __shared__ alignas(16) float sh_out[ROWS_PER_BLOCK * NT];   // 36 KiB
    const int tid = threadIdx.x;
    if (tid < NT) {
        sh_t[tid]  = t[tid];
        sh_re[tid] = R[tid] * sinf(alpha[tid] * 0.017453292519943295f);
    }
    __syncthreads();

    const int c   = tid & 3;          // which j-chunk phase
    const int r   = tid >> 2;         // local row 0..63
    const int row = blockIdx.x * ROWS_PER_BLOCK + r;

    if (row < B) {
        const float4 xi = reinterpret_cast<const float4*>(x)[row];
        const float dt  = xi.x;
        const float s   = xi.y;
        const float p   = xi.z;
        const float amp = xi.w;

        const float T1B   = 1.65f;
        const float TAU   = 1.8f;
        const float LOG2E = 1.4426950408889634f;

        const float u  = p * s;            // a-1 in [0,1)
        const float a  = 1.0f + u;
        const float sp = s + (1.0f / T1B);

        // Gamma(1+u), u in [0,1): A&S 6.1.36, |err| <= 3e-7
        float g = 0.035868343f;
        g = g * u - 0.193527818f;
        g = g * u + 0.482199394f;
        g = g * u - 0.756704078f;
        g = g * u + 0.918206857f;
        g = g * u - 0.897056937f;
        g = g * u + 0.988205891f;
        g = g * u - 0.577191652f;
        g = g * u + 1.0f;
        const float Ga1 = (1.0f + u) * g;  // Gamma(a+1)

        // d_k = prod_{m=k..18}(a+m) -- named scalars (VGPRs, no scratch)
        const float d18 = a + 18.0f;
        const float d17 = (a + 17.0f) * d18;
        const float d16 = (a + 16.0f) * d17;
        const float d15 = (a + 15.0f) * d16;
        const float d14 = (a + 14.0f) * d15;
        const float d13 = (a + 13.0f) * d14;
        const float d12 = (a + 12.0f) * d13;
        const float d11 = (a + 11.0f) * d12;
        const float d10 = (a + 10.0f) * d11;
        const float d9  = (a +  9.0f) * d10;
        const float d8  = (a +  8.0f) * d9;
        const float d7  = (a +  7.0f) * d8;
        const float d6  = (a +  6.0f) * d7;
        const float d5  = (a +  5.0f) * d6;
        const float d4  = (a +  4.0f) * d5;
        const float d3  = (a +  3.0f) * d4;
        const float d2  = (a +  2.0f) * d3;
        const float d1  = (a +  1.0f) * d2;

        const float invDG = 1.0f / (d1 * Ga1);

        // SF = 2*exp(-dt/T1B)*(s/sp)^a  (per-row hw transc, amortized)
        const float SF = 2.0f * __builtin_amdgcn_exp2f(
            a * (__builtin_amdgcn_logf(s) - __builtin_amdgcn_logf(sp))
            - dt * (LOG2E / T1B));

        const float crow  = amp * SF * invDG;
        const float nspdt = -sp * dt;
        const float spTau = sp * TAU;

        // One full evaluation: 36 v_fma + 2 v_log + 2 v_exp (+ misc).
        auto core = [&](float x1, float x2) -> float {
            const float l1 = __builtin_amdgcn_logf(x1);
            const float l2 = __builtin_amdgcn_logf(x2);       // log(0)=-inf ok
            float n1 = x1 + d18;
            float n2 = x2 + d18;
            n1 = __builtin_fmaf(n1, x1, d17);  n2 = __builtin_fmaf(n2, x2, d17);
            n1 = __builtin_fmaf(n1, x1, d16);  n2 = __builtin_fmaf(n2, x2, d16);
            n1 = __builtin_fmaf(n1, x1, d15);  n2 = __builtin_fmaf(n2, x2, d15);
            n1 = __builtin_fmaf(n1, x1, d14);  n2 = __builtin_fmaf(n2, x2, d14);
            n1 = __builtin_fmaf(n1, x1, d13);  n2 = __builtin_fmaf(n2, x2, d13);
            n1 = __builtin_fmaf(n1, x1, d12);  n2 = __builtin_fmaf(n2, x2, d12);
            n1 = __builtin_fmaf(n1, x1, d11);  n2 = __builtin_fmaf(n2, x2, d11);
            n1 = __builtin_fmaf(n1, x1, d10);  n2 = __builtin_fmaf(n2, x2, d10);
            n1 = __builtin_fmaf(n1, x1, d9);   n2 = __builtin_fmaf(n2, x2, d9);
            n1 = __builtin_fmaf(n1, x1, d8);   n2 = __builtin_fmaf(n2, x2, d8);
            n1 = __builtin_fmaf(n1, x1, d7);   n2 = __builtin_fmaf(n2, x2, d7);
            n1 = __builtin_fmaf(n1, x1, d6);   n2 = __builtin_fmaf(n2, x2, d6);
            n1 = __builtin_fmaf(n1, x1, d5);   n2 = __builtin_fmaf(n2, x2, d5);
            n1 = __builtin_fmaf(n1, x1, d4);   n2 = __builtin_fmaf(n2, x2, d4);
            n1 = __builtin_fmaf(n1, x1, d3);   n2 = __builtin_fmaf(n2, x2, d3);
            n1 = __builtin_fmaf(n1, x1, d2);   n2 = __builtin_fmaf(n2, x2, d2);
            n1 = __builtin_fmaf(n1, x1, d1);   n2 = __builtin_fmaf(n2, x2, d1);
            const float e1 = __builtin_amdgcn_exp2f(
                __builtin_fmaf(a, l1, -(x1 * LOG2E)));
            const float e2 = __builtin_amdgcn_exp2f(
                __builtin_fmaf(a, l2, -(x2 * LOG2E)));
            return __builtin_fmaf(n1, e1, -(n2 * e2));
        };

        auto elem = [&](float tj, float cr) -> float {
            const float x1 = __builtin_fmaf(sp, tj, nspdt);   // > 0.48 always
            const float x2 = fmaxf(x1 - spTau, 0.0f);
            const float r1 = core(x1, x2);
            // DIAGNOSTIC: recompute through opaque copies (CSE-blocked),
            // average bit-exactly. 0.5*(r+r) == r in f32.
            float x1b = x1, x2b = x2;
            asm volatile("" : "+v"(x1b), "+v"(x2b));
            const float r2 = core(x1b, x2b);
            return cr * (0.5f * (r1 + r2));
        };

        v4f* __restrict__ srow4 = reinterpret_cast<v4f*>(sh_out) + r * (NT / 4);
        const v4f* sh_t4  = reinterpret_cast<const v4f*>(sh_t);
        const v4f* sh_re4 = reinterpret_cast<const v4f*>(sh_re);

        v4f tj4 = sh_t4[c];
        v4f re4 = sh_re4[c];

        #pragma unroll 1
        for (int k = 0; k < 9; ++k) {
            const int ch  = c + 4 * k;             // chunk index 0..35
            const int chn = (k < 8) ? ch + 4 : ch; // clamp: no OOB on last iter
            const v4f tj4n = sh_t4[chn];
            const v4f re4n = sh_re4[chn];
            v4f res;
            res.x = elem(tj4.x, crow * re4.x);
            res.y = elem(tj4.y, crow * re4.y);
            res.z = elem(tj4.z, crow * re4.z);
            res.w = elem(tj4.w, crow * re4.w);
            srow4[ch] = res;                       // ds_write_b128, stays on-CU
            tj4 = tj4n;
            re4 = re4n;
        }
    }

    __syncthreads();

    // Linear flush (identical to R6): block's 36 KiB contiguous in out.
    v4f* __restrict__ outp =
        reinterpret_cast<v4f*>(out) + (size_t)blockIdx.x * F4_PER_BLOCK;
    const v4f* so4 = reinterpret_cast<const v4f*>(sh_out);

    #pragma unroll
    for (int k2 = 0; k2 < 9; ++k2) {
        const int f = k2 * 256 + tid;
        __builtin_nontemporal_store(so4[f], &outp[f]);
    }
}

extern "C" void kernel_launch(void* const* d_in, const int* in_sizes, int n_in,
                              void* d_out, int out_size, void* d_ws, size_t ws_size,
                              hipStream_t stream) {
    const float* x     = (const float*)d_in[0];
    const float* t     = (const float*)d_in[1];
    const float* alpha = (const float*)d_in[2];
    const float* R     = (const float*)d_in[3];
    float* out = (float*)d_out;

    const int B = in_sizes[0] / 4;
    const int blocks = (B + ROWS_PER_BLOCK - 1) / ROWS_PER_BLOCK;
    hipLaunchKernelGGL(dynangio_kernel, dim3(blocks), dim3(256), 0, stream,
                       x, t, alpha, R, out, B);
}

// Round 8
// 180.835 us; speedup vs baseline: 1.1701x; 1.1701x over previous
//
#include <hip/hip_runtime.h>
#include <cmath>

#define NT 144

typedef float v4f __attribute__((ext_vector_type(4)));

// Round-10: OCCUPANCY / ISSUE-EFFICIENCY. R7's calibrated diagnostic proved:
//   * base kernel T < 58 us (doubled version still < 93.8 us top-5 cutoff)
//   * marginal core cost = 35.6 us => compute ~36 us, ~25% issue bubbles
//     vs the 28.8 us ideal-issue model (120 cy/elem: 36 FMA + 4 trans + misc)
//   * dur_us carries ~40 us of fixed non-kernel cost + ~94 us poison fill,
//     which is why R0-R6's structural changes were invisible.
//   * packed-vs-scalar null explained: v_pk_fma_f32 is half-rate (fp32 peak
//     157.3 TF), so 18 packed == 36 scalar == 72 cy. Both at the same floor.
// Changes (both target issue bubbles / latency hiding):
//   1. Drop LDS out-staging + barrier (R6 proved store pattern irrelevant):
//      direct NT strided stores, LDS shrinks 38 -> 1.2 KiB, no convoy barrier.
//   2. __launch_bounds__(256,6): <=85 VGPR, 6 waves/SIMD (was 4) -> more
//      independent trans->fma->exp chains resident per SIMD.

__global__ __launch_bounds__(256, 6) void dynangio_kernel(
    const float* __restrict__ x,
    const float* __restrict__ t,
    const float* __restrict__ alpha,
    const float* __restrict__ R,
    float* __restrict__ out,
    int B)
{
    __shared__ alignas(16) float sh_t[NT];
    __shared__ alignas(16) float sh_re[NT];
    const int tid = threadIdx.x;
    if (tid < NT) {
        sh_t[tid]  = t[tid];
        sh_re[tid] = R[tid] * sinf(alpha[tid] * 0.017453292519943295f);
    }
    __syncthreads();

    const int c   = tid & 3;          // which j-chunk phase
    const int row = blockIdx.x * 64 + (tid >> 2);
    if (row >= B) return;

    const float4 xi = reinterpret_cast<const float4*>(x)[row];
    const float dt  = xi.x;
    const float s   = xi.y;
    const float p   = xi.z;
    const float amp = xi.w;

    const float T1B   = 1.65f;
    const float TAU   = 1.8f;
    const float LOG2E = 1.4426950408889634f;

    const float u  = p * s;            // a-1 in [0,1)
    const float a  = 1.0f + u;
    const float sp = s + (1.0f / T1B);

    // Gamma(1+u), u in [0,1): A&S 6.1.36, |err| <= 3e-7
    float g = 0.035868343f;
    g = g * u - 0.193527818f;
    g = g * u + 0.482199394f;
    g = g * u - 0.756704078f;
    g = g * u + 0.918206857f;
    g = g * u - 0.897056937f;
    g = g * u + 0.988205891f;
    g = g * u - 0.577191652f;
    g = g * u + 1.0f;
    const float Ga1 = (1.0f + u) * g;  // Gamma(a+1)

    // d_k = prod_{m=k..18}(a+m) -- named scalars (VGPRs, no scratch)
    const float d18 = a + 18.0f;
    const float d17 = (a + 17.0f) * d18;
    const float d16 = (a + 16.0f) * d17;
    const float d15 = (a + 15.0f) * d16;
    const float d14 = (a + 14.0f) * d15;
    const float d13 = (a + 13.0f) * d14;
    const float d12 = (a + 12.0f) * d13;
    const float d11 = (a + 11.0f) * d12;
    const float d10 = (a + 10.0f) * d11;
    const float d9  = (a +  9.0f) * d10;
    const float d8  = (a +  8.0f) * d9;
    const float d7  = (a +  7.0f) * d8;
    const float d6  = (a +  6.0f) * d7;
    const float d5  = (a +  5.0f) * d6;
    const float d4  = (a +  4.0f) * d5;
    const float d3  = (a +  3.0f) * d4;
    const float d2  = (a +  2.0f) * d3;
    const float d1  = (a +  1.0f) * d2;

    const float invDG = 1.0f / (d1 * Ga1);

    // SF = 2*exp(-dt/T1B)*(s/sp)^a  (per-row hw transc, amortized)
    const float SF = 2.0f * __builtin_amdgcn_exp2f(
        a * (__builtin_amdgcn_logf(s) - __builtin_amdgcn_logf(sp))
        - dt * (LOG2E / T1B));

    const float crow  = amp * SF * invDG;
    const float nspdt = -sp * dt;
    const float spTau = sp * TAU;

    // Fully scalar element: 36 v_fma_f32 + 2 v_log + 2 v_exp + ~8 misc.
    auto elem = [&](float tj, float cr) -> float {
        const float x1 = __builtin_fmaf(sp, tj, nspdt);   // > 0.48 always
        const float x2 = fmaxf(x1 - spTau, 0.0f);
        const float l1 = __builtin_amdgcn_logf(x1);
        const float l2 = __builtin_amdgcn_logf(x2);       // log(0)=-inf ok
        float n1 = x1 + d18;
        float n2 = x2 + d18;
        n1 = __builtin_fmaf(n1, x1, d17);  n2 = __builtin_fmaf(n2, x2, d17);
        n1 = __builtin_fmaf(n1, x1, d16);  n2 = __builtin_fmaf(n2, x2, d16);
        n1 = __builtin_fmaf(n1, x1, d15);  n2 = __builtin_fmaf(n2, x2, d15);
        n1 = __builtin_fmaf(n1, x1, d14);  n2 = __builtin_fmaf(n2, x2, d14);
        n1 = __builtin_fmaf(n1, x1, d13);  n2 = __builtin_fmaf(n2, x2, d13);
        n1 = __builtin_fmaf(n1, x1, d12);  n2 = __builtin_fmaf(n2, x2, d12);
        n1 = __builtin_fmaf(n1, x1, d11);  n2 = __builtin_fmaf(n2, x2, d11);
        n1 = __builtin_fmaf(n1, x1, d10);  n2 = __builtin_fmaf(n2, x2, d10);
        n1 = __builtin_fmaf(n1, x1, d9);   n2 = __builtin_fmaf(n2, x2, d9);
        n1 = __builtin_fmaf(n1, x1, d8);   n2 = __builtin_fmaf(n2, x2, d8);
        n1 = __builtin_fmaf(n1, x1, d7);   n2 = __builtin_fmaf(n2, x2, d7);
        n1 = __builtin_fmaf(n1, x1, d6);   n2 = __builtin_fmaf(n2, x2, d6);
        n1 = __builtin_fmaf(n1, x1, d5);   n2 = __builtin_fmaf(n2, x2, d5);
        n1 = __builtin_fmaf(n1, x1, d4);   n2 = __builtin_fmaf(n2, x2, d4);
        n1 = __builtin_fmaf(n1, x1, d3);   n2 = __builtin_fmaf(n2, x2, d3);
        n1 = __builtin_fmaf(n1, x1, d2);   n2 = __builtin_fmaf(n2, x2, d2);
        n1 = __builtin_fmaf(n1, x1, d1);   n2 = __builtin_fmaf(n2, x2, d1);
        const float e1 = __builtin_amdgcn_exp2f(
            __builtin_fmaf(a, l1, -(x1 * LOG2E)));
        const float e2 = __builtin_amdgcn_exp2f(
            __builtin_fmaf(a, l2, -(x2 * LOG2E)));
        return cr * __builtin_fmaf(n1, e1, -(n2 * e2));
    };

    v4f* __restrict__ orow4 = reinterpret_cast<v4f*>(out + (size_t)row * NT);
    const v4f* sh_t4  = reinterpret_cast<const v4f*>(sh_t);
    const v4f* sh_re4 = reinterpret_cast<const v4f*>(sh_re);

    // Software-pipelined LDS reads: next chunk's t/re load before current math.
    v4f tj4 = sh_t4[c];
    v4f re4 = sh_re4[c];

    #pragma unroll 1
    for (int k = 0; k < 9; ++k) {
        const int ch  = c + 4 * k;             // chunk index 0..35
        const int chn = (k < 8) ? ch + 4 : ch; // clamp: no OOB on last iter
        const v4f tj4n = sh_t4[chn];
        const v4f re4n = sh_re4[chn];
        v4f res;
        res.x = elem(tj4.x, crow * re4.x);
        res.y = elem(tj4.y, crow * re4.y);
        res.z = elem(tj4.z, crow * re4.z);
        res.w = elem(tj4.w, crow * re4.w);
        __builtin_nontemporal_store(res, &orow4[ch]);
        tj4 = tj4n;
        re4 = re4n;
    }
}

extern "C" void kernel_launch(void* const* d_in, const int* in_sizes, int n_in,
                              void* d_out, int out_size, void* d_ws, size_t ws_size,
                              hipStream_t stream) {
    const float* x     = (const float*)d_in[0];
    const float* t     = (const float*)d_in[1];
    const float* alpha = (const float*)d_in[2];
    const float* R     = (const float*)d_in[3];
    float* out = (float*)d_out;

    const int B = in_sizes[0] / 4;
    const int rows_per_block = 64;
    const int blocks = (B + rows_per_block - 1) / rows_per_block;
    hipLaunchKernelGGL(dynangio_kernel, dim3(blocks), dim3(256), 0, stream,
                       x, t, alpha, R, out, B);
}